// Round 1
// baseline (308.209 us; speedup 1.0000x reference)
//
#include <hip/hip_runtime.h>
#include <hip/hip_bf16.h>
#include <math.h>

// Problem constants
#define Bn   2
#define Nn   2048
#define Kn   48
#define Cn   128
#define Hn   128
#define INn  384

typedef short bf16x8 __attribute__((ext_vector_type(8)));
typedef float f32x4  __attribute__((ext_vector_type(4)));

__device__ __forceinline__ short f2bf(float f) {
  union { float f; unsigned u; } v; v.f = f;
  unsigned r = v.u + 0x7fffu + ((v.u >> 16) & 1u);
  return (short)(r >> 16);
}

// ---------------------------------------------------------------------------
// Pack W1 (384x128), W2 (128x128), W3 (128x128) fp32 row-major into bf16
// MFMA B-fragment tiles. Tile (kt,nt) = 1024 B; lane l holds 8 bf16 =
// W[kt*32 + (l>>4)*8 + j][nt*16 + (l&15)], j=0..7 (k-contiguous in vector).
// ws layout (shorts): W1p [0,49152) W2p [49152,65536) W3p [65536,81920)
// ---------------------------------------------------------------------------
__global__ void pack_weights(const float* __restrict__ W1,
                             const float* __restrict__ W2,
                             const float* __restrict__ W3,
                             short* __restrict__ ws) {
  int tid = blockIdx.x * blockDim.x + threadIdx.x;
  if (tid >= 160 * 64) return;
  int lane = tid & 63;
  int tile = tid >> 6;
  const float* W; short* dst;
  if (tile < 96)       { W = W1; dst = ws; }
  else if (tile < 128) { W = W2; dst = ws + 49152; tile -= 96; }
  else                 { W = W3; dst = ws + 65536; tile -= 128; }
  int kt = tile >> 3, nt = tile & 7;
  int n  = nt * 16 + (lane & 15);
  int k0 = kt * 32 + (lane >> 4) * 8;
  union { short s[8]; bf16x8 v; } u8;
#pragma unroll
  for (int j = 0; j < 8; j++) u8.s[j] = f2bf(W[(k0 + j) * 128 + n]);
  *reinterpret_cast<bf16x8*>(dst + (tile << 9) + lane * 8) = u8.v;
}

// Block reduction of two values across 256 threads (all threads must call).
__device__ __forceinline__ void block_reduce2(float v1, float v2, float* red,
                                              int tid, float& o1, float& o2) {
#pragma unroll
  for (int off = 32; off >= 1; off >>= 1) {
    v1 += __shfl_xor(v1, off);
    v2 += __shfl_xor(v2, off);
  }
  if ((tid & 63) == 0) { red[tid >> 6] = v1; red[4 + (tid >> 6)] = v2; }
  __syncthreads();
  o1 = red[0] + red[1] + red[2] + red[3];
  o2 = red[4] + red[5] + red[6] + red[7];
  __syncthreads();
}

// ---------------------------------------------------------------------------
// One block per node (b,n). 256 threads = 4 waves; wave w owns output
// columns [w*32, w*32+32) (2 ntiles of 16). M = 48 edges = 3 mtiles.
// ---------------------------------------------------------------------------
__global__ __launch_bounds__(256, 3)
void node_update_kernel(const float* __restrict__ node_h,
                        const float* __restrict__ edge_h,
                        const int*   __restrict__ edge_index,
                        const short* __restrict__ wpack,
                        const float* __restrict__ b1,
                        const float* __restrict__ b2,
                        const float* __restrict__ b3,
                        const float* __restrict__ Wu,
                        const float* __restrict__ bu,
                        const float* __restrict__ ln_g,
                        const float* __restrict__ ln_b,
                        float* __restrict__ out) {
  // LDS layout (aliased regions — lifetimes commented):
  //   [0,37632)      Xs: 48 x (384+8) bf16   (dead after GEMM1)
  //   [0,13056)      H2s: 48 x (128+8) bf16  (written in GEMM2 epilogue)
  //   [37632,50688)  H1s: 48 x (128+8) bf16  (dead after GEMM2 reads)
  //     overlay:     u_s[128]f32 @37632 | part_s[256]f32 @38144 | red_s[8]f32 @39168
  //   [50688,51200)  msg_s[128] f32
  //   [51200,51392)  idx_s[48] int
  __shared__ __align__(16) char smem[51392];
  short* Xs    = (short*)smem;
  short* H2s   = (short*)smem;
  short* H1s   = (short*)(smem + 37632);
  float* u_s   = (float*)(smem + 37632);
  float* part_s= (float*)(smem + 38144);
  float* red_s = (float*)(smem + 39168);
  float* msg_s = (float*)(smem + 50688);
  int*   idx_s = (int*)  (smem + 51200);

  const int tid  = threadIdx.x;
  const int blk  = blockIdx.x;          // = b*N + n
  const int bb   = blk >> 11;           // b  (N = 2048)
  const int lane = tid & 63;
  const int wave = tid >> 6;
  const int lr   = lane & 15;           // A-row / B-col / D-col within tile
  const int lq   = lane >> 4;           // quad

  if (tid < 48) idx_s[tid] = edge_index[blk * Kn + tid];
  __syncthreads();

  // ---- stage X = [node_i | node_j | edge_h] as bf16 rows (stride 392) ----
  {
    const float* nh_i = node_h + (size_t)blk * Cn;
    for (int i = tid; i < 48 * 96; i += 256) {
      int r = i / 96;
      int c = (i % 96) * 4;
      const float* src;
      if (c < 128)      src = nh_i + c;
      else if (c < 256) src = node_h + (size_t)(bb * Nn + idx_s[r]) * Cn + (c - 128);
      else              src = edge_h + ((size_t)blk * Kn + r) * 128 + (c - 256);
      float4 v = *reinterpret_cast<const float4*>(src);
      union { short s[4]; unsigned long long u; } p;
      p.s[0] = f2bf(v.x); p.s[1] = f2bf(v.y);
      p.s[2] = f2bf(v.z); p.s[3] = f2bf(v.w);
      *reinterpret_cast<unsigned long long*>(&Xs[r * 392 + c]) = p.u;
    }
  }
  __syncthreads();

  const short* W1p = wpack;
  const short* W2p = wpack + 49152;
  const short* W3p = wpack + 65536;

  // ---------------- GEMM1: (48x384) @ W1 -> gelu -> H1s ----------------
  f32x4 acc[3][2] = {};
#pragma unroll
  for (int kt = 0; kt < 12; kt++) {
    bf16x8 bf0 = *reinterpret_cast<const bf16x8*>(W1p + ((kt * 8 + wave * 2 + 0) << 9) + lane * 8);
    bf16x8 bf1 = *reinterpret_cast<const bf16x8*>(W1p + ((kt * 8 + wave * 2 + 1) << 9) + lane * 8);
    int ko = kt * 32 + lq * 8;
    bf16x8 a0 = *reinterpret_cast<const bf16x8*>(&Xs[(0  + lr) * 392 + ko]);
    bf16x8 a1 = *reinterpret_cast<const bf16x8*>(&Xs[(16 + lr) * 392 + ko]);
    bf16x8 a2 = *reinterpret_cast<const bf16x8*>(&Xs[(32 + lr) * 392 + ko]);
    acc[0][0] = __builtin_amdgcn_mfma_f32_16x16x32_bf16(a0, bf0, acc[0][0], 0, 0, 0);
    acc[0][1] = __builtin_amdgcn_mfma_f32_16x16x32_bf16(a0, bf1, acc[0][1], 0, 0, 0);
    acc[1][0] = __builtin_amdgcn_mfma_f32_16x16x32_bf16(a1, bf0, acc[1][0], 0, 0, 0);
    acc[1][1] = __builtin_amdgcn_mfma_f32_16x16x32_bf16(a1, bf1, acc[1][1], 0, 0, 0);
    acc[2][0] = __builtin_amdgcn_mfma_f32_16x16x32_bf16(a2, bf0, acc[2][0], 0, 0, 0);
    acc[2][1] = __builtin_amdgcn_mfma_f32_16x16x32_bf16(a2, bf1, acc[2][1], 0, 0, 0);
  }
#pragma unroll
  for (int j = 0; j < 2; j++) {
    int col = (wave * 2 + j) * 16 + lr;
    float bias = b1[col];
#pragma unroll
    for (int mt = 0; mt < 3; mt++) {
#pragma unroll
      for (int r = 0; r < 4; r++) {
        int row = mt * 16 + lq * 4 + r;
        float x = acc[mt][j][r] + bias;
        float g = 0.5f * x * (1.0f + erff(x * 0.70710678118654752f));
        H1s[row * 136 + col] = f2bf(g);
      }
    }
  }
  __syncthreads();

  // ---------------- GEMM2: (48x128) @ W2 -> gelu -> H2s (overlays Xs) ----
  f32x4 acc2[3][2] = {};
#pragma unroll
  for (int kt = 0; kt < 4; kt++) {
    bf16x8 bf0 = *reinterpret_cast<const bf16x8*>(W2p + ((kt * 8 + wave * 2 + 0) << 9) + lane * 8);
    bf16x8 bf1 = *reinterpret_cast<const bf16x8*>(W2p + ((kt * 8 + wave * 2 + 1) << 9) + lane * 8);
    int ko = kt * 32 + lq * 8;
    bf16x8 a0 = *reinterpret_cast<const bf16x8*>(&H1s[(0  + lr) * 136 + ko]);
    bf16x8 a1 = *reinterpret_cast<const bf16x8*>(&H1s[(16 + lr) * 136 + ko]);
    bf16x8 a2 = *reinterpret_cast<const bf16x8*>(&H1s[(32 + lr) * 136 + ko]);
    acc2[0][0] = __builtin_amdgcn_mfma_f32_16x16x32_bf16(a0, bf0, acc2[0][0], 0, 0, 0);
    acc2[0][1] = __builtin_amdgcn_mfma_f32_16x16x32_bf16(a0, bf1, acc2[0][1], 0, 0, 0);
    acc2[1][0] = __builtin_amdgcn_mfma_f32_16x16x32_bf16(a1, bf0, acc2[1][0], 0, 0, 0);
    acc2[1][1] = __builtin_amdgcn_mfma_f32_16x16x32_bf16(a1, bf1, acc2[1][1], 0, 0, 0);
    acc2[2][0] = __builtin_amdgcn_mfma_f32_16x16x32_bf16(a2, bf0, acc2[2][0], 0, 0, 0);
    acc2[2][1] = __builtin_amdgcn_mfma_f32_16x16x32_bf16(a2, bf1, acc2[2][1], 0, 0, 0);
  }
  __syncthreads();   // all H1s reads done before H2s (disjoint) writes race anyway; keep for clarity
#pragma unroll
  for (int j = 0; j < 2; j++) {
    int col = (wave * 2 + j) * 16 + lr;
    float bias = b2[col];
#pragma unroll
    for (int mt = 0; mt < 3; mt++) {
#pragma unroll
      for (int r = 0; r < 4; r++) {
        int row = mt * 16 + lq * 4 + r;
        float x = acc2[mt][j][r] + bias;
        float g = 0.5f * x * (1.0f + erff(x * 0.70710678118654752f));
        H2s[row * 136 + col] = f2bf(g);
      }
    }
  }
  __syncthreads();

  // ---------------- GEMM3: (48x128) @ W3, column-sum over 48 edges -------
  f32x4 acc3[3][2] = {};
#pragma unroll
  for (int kt = 0; kt < 4; kt++) {
    bf16x8 bf0 = *reinterpret_cast<const bf16x8*>(W3p + ((kt * 8 + wave * 2 + 0) << 9) + lane * 8);
    bf16x8 bf1 = *reinterpret_cast<const bf16x8*>(W3p + ((kt * 8 + wave * 2 + 1) << 9) + lane * 8);
    int ko = kt * 32 + lq * 8;
    bf16x8 a0 = *reinterpret_cast<const bf16x8*>(&H2s[(0  + lr) * 136 + ko]);
    bf16x8 a1 = *reinterpret_cast<const bf16x8*>(&H2s[(16 + lr) * 136 + ko]);
    bf16x8 a2 = *reinterpret_cast<const bf16x8*>(&H2s[(32 + lr) * 136 + ko]);
    acc3[0][0] = __builtin_amdgcn_mfma_f32_16x16x32_bf16(a0, bf0, acc3[0][0], 0, 0, 0);
    acc3[0][1] = __builtin_amdgcn_mfma_f32_16x16x32_bf16(a0, bf1, acc3[0][1], 0, 0, 0);
    acc3[1][0] = __builtin_amdgcn_mfma_f32_16x16x32_bf16(a1, bf0, acc3[1][0], 0, 0, 0);
    acc3[1][1] = __builtin_amdgcn_mfma_f32_16x16x32_bf16(a1, bf1, acc3[1][1], 0, 0, 0);
    acc3[2][0] = __builtin_amdgcn_mfma_f32_16x16x32_bf16(a2, bf0, acc3[2][0], 0, 0, 0);
    acc3[2][1] = __builtin_amdgcn_mfma_f32_16x16x32_bf16(a2, bf1, acc3[2][1], 0, 0, 0);
  }
#pragma unroll
  for (int j = 0; j < 2; j++) {
    int col = (wave * 2 + j) * 16 + lr;
    float s = 0.f;
#pragma unroll
    for (int mt = 0; mt < 3; mt++)
#pragma unroll
      for (int r = 0; r < 4; r++) s += acc3[mt][j][r];
    // rows covered so far: {lq*4+r, +16, +32}; fold quads to get all 48
    s += __shfl_xor(s, 16);
    s += __shfl_xor(s, 32);
    if (lq == 0) msg_s[col] = (s + 48.0f * b3[col]) * (1.0f / 30.0f);
  }
  __syncthreads();

  // ---------------- LN -> u ; u@Wu+bu ; LN -> out ------------------------
  const int c    = tid & 127;
  const int half = tid >> 7;
  float nh = node_h[(size_t)blk * Cn + c];
  float x  = (half == 0) ? (nh + msg_s[c]) : 0.f;

  float sum, sumsq;
  block_reduce2(x, x * x, red_s, tid, sum, sumsq);
  float mu   = sum * (1.f / 128.f);
  float var  = sumsq * (1.f / 128.f) - mu * mu;
  float rstd = rsqrtf(var + 1e-5f);
  if (half == 0) u_s[c] = (x - mu) * rstd * ln_g[c] + ln_b[c];
  __syncthreads();

  {
    float a = 0.f;
    const int j0 = half * 64;
#pragma unroll 8
    for (int j = 0; j < 64; j++)
      a += u_s[j0 + j] * Wu[(j0 + j) * 128 + c];
    part_s[tid] = a;
  }
  __syncthreads();

  float y = (half == 0) ? (nh + part_s[c] + part_s[128 + c] + bu[c]) : 0.f;
  float sum2, sumsq2;
  block_reduce2(y, y * y, red_s, tid, sum2, sumsq2);
  float mu2   = sum2 * (1.f / 128.f);
  float var2  = sumsq2 * (1.f / 128.f) - mu2 * mu2;
  float rstd2 = rsqrtf(var2 + 1e-5f);
  if (half == 0)
    out[(size_t)blk * Cn + c] = (y - mu2) * rstd2 * ln_g[c] + ln_b[c];
}

extern "C" void kernel_launch(void* const* d_in, const int* in_sizes, int n_in,
                              void* d_out, int out_size, void* d_ws, size_t ws_size,
                              hipStream_t stream) {
  const float* node_h     = (const float*)d_in[0];
  const float* edge_h     = (const float*)d_in[1];
  const int*   edge_index = (const int*)  d_in[2];
  const float* W1 = (const float*)d_in[3];
  const float* b1 = (const float*)d_in[4];
  const float* W2 = (const float*)d_in[5];
  const float* b2 = (const float*)d_in[6];
  const float* W3 = (const float*)d_in[7];
  const float* b3 = (const float*)d_in[8];
  const float* Wu = (const float*)d_in[9];
  const float* bu = (const float*)d_in[10];
  const float* ln_g = (const float*)d_in[11];
  const float* ln_b = (const float*)d_in[12];
  float* out   = (float*)d_out;
  short* wpack = (short*)d_ws;   // needs 160 KiB

  pack_weights<<<40, 256, 0, stream>>>(W1, W2, W3, wpack);
  node_update_kernel<<<Bn * Nn, 256, 0, stream>>>(
      node_h, edge_h, edge_index, wpack,
      b1, b2, b3, Wu, bu, ln_g, ln_b, out);
}

// Round 2
// 251.639 us; speedup vs baseline: 1.2248x; 1.2248x over previous
//
#include <hip/hip_runtime.h>
#include <hip/hip_bf16.h>
#include <math.h>

// Problem constants
#define Bn   2
#define Nn   2048
#define Kn   48
#define Cn   128
#define Hn   128

typedef short bf16x8 __attribute__((ext_vector_type(8)));
typedef float f32x4  __attribute__((ext_vector_type(4)));

__device__ __forceinline__ short f2bf(float f) {
  union { float f; unsigned u; } v; v.f = f;
  unsigned r = v.u + 0x7fffu + ((v.u >> 16) & 1u);
  return (short)(r >> 16);
}

// fast tanh-GELU: gelu(x) = x * sigmoid(1.5957691216*(x + 0.044715 x^3))
//                         = x / (1 + exp(-2*0.7978845608*(x+0.044715x^3)))
// max abs deviation from erf-gelu ~3e-4 (<< bf16 rounding noise here).
__device__ __forceinline__ float gelu_f(float x) {
  float z = x * (-1.5957691216f - 0.0713548163f * x * x);
  return x / (1.0f + __expf(z));
}

// ---------------------------------------------------------------------------
// Pack W1[128:384] (256x128), W2 (128x128), W3 (128x128) fp32 row-major into
// bf16 MFMA B-fragment tiles. Tile (kt,nt) = 512 shorts; lane l holds 8 bf16 =
// W[kt*32 + (l>>4)*8 + j][nt*16 + (l&15)], j=0..7 (k-contiguous in vector).
// ws layout (shorts): W1p [0,32768) W2p [32768,49152) W3p [49152,65536)
// (W1 rows 0..127 are the node_i contribution, handled as an fp32 matvec.)
// ---------------------------------------------------------------------------
__global__ void pack_weights(const float* __restrict__ W1,
                             const float* __restrict__ W2,
                             const float* __restrict__ W3,
                             short* __restrict__ ws) {
  int tid = blockIdx.x * blockDim.x + threadIdx.x;
  if (tid >= 128 * 64) return;
  int lane = tid & 63;
  int tile = tid >> 6;
  const float* W; short* dst;
  if (tile < 64)       { W = W1 + 128 * 128; dst = ws; }
  else if (tile < 96)  { W = W2; dst = ws + 32768; tile -= 64; }
  else                 { W = W3; dst = ws + 49152; tile -= 96; }
  int kt = tile >> 3, nt = tile & 7;
  int n  = nt * 16 + (lane & 15);
  int k0 = kt * 32 + (lane >> 4) * 8;
  union { short s[8]; bf16x8 v; } u8;
#pragma unroll
  for (int j = 0; j < 8; j++) u8.s[j] = f2bf(W[(k0 + j) * 128 + n]);
  *reinterpret_cast<bf16x8*>(dst + (tile << 9) + lane * 8) = u8.v;
}

// Block reduction of two values across 256 threads (all threads must call).
__device__ __forceinline__ void block_reduce2(float v1, float v2, float* red,
                                              int tid, float& o1, float& o2) {
#pragma unroll
  for (int off = 32; off >= 1; off >>= 1) {
    v1 += __shfl_xor(v1, off);
    v2 += __shfl_xor(v2, off);
  }
  if ((tid & 63) == 0) { red[tid >> 6] = v1; red[4 + (tid >> 6)] = v2; }
  __syncthreads();
  o1 = red[0] + red[1] + red[2] + red[3];
  o2 = red[4] + red[5] + red[6] + red[7];
  __syncthreads();
}

// ---------------------------------------------------------------------------
// One block per node (b,n). 256 threads = 4 waves; wave w owns output
// columns [w*32, w*32+32). M = 48 edges = 3 mtiles of 16.
// LDS rows are XOR-swizzled on 16B granules: addr(r,c) =
//   r*STRIDE + (((c>>3) ^ (r&7))<<3) + (c&7)   [shorts]
// STRIDE is a multiple of 64 shorts (32 dwords) so b128 A-frag reads hit each
// bank-quad with exactly 8 lanes (the 8-cycle service minimum = conflict-free).
// ---------------------------------------------------------------------------
__global__ __launch_bounds__(256, 4)
void node_update_kernel(const float* __restrict__ node_h,
                        const float* __restrict__ edge_h,
                        const int*   __restrict__ edge_index,
                        const short* __restrict__ wpack,
                        const float* __restrict__ W1,
                        const float* __restrict__ b1,
                        const float* __restrict__ b2,
                        const float* __restrict__ b3,
                        const float* __restrict__ Wu,
                        const float* __restrict__ bu,
                        const float* __restrict__ ln_g,
                        const float* __restrict__ ln_b,
                        float* __restrict__ out) {
  // LDS layout (bytes):
  //   [0,24576)      Xs : 48 x 256 bf16 (node_j|edge_h), swizzled. Dead after GEMM1.
  //   [0,12288)      H2s: 48 x 128 bf16, swizzled (overlays Xs)
  //   [24576,36864)  H1s: 48 x 128 bf16, swizzled
  //   [36864,37376)  nhs[128] f32 (node_i)
  //   [37376,38400)  part_s[256] f32
  //   [38400,38432)  red_s[8] f32
  //   [38432,38944)  msg_s[128] f32
  //   [38944,39456)  u_s[128] f32
  //   [39456,39648)  idx_s[48] int
  __shared__ __align__(16) char smem[39648];
  short* Xs    = (short*)smem;
  short* H2s   = (short*)smem;
  short* H1s   = (short*)(smem + 24576);
  float* nhs   = (float*)(smem + 36864);
  float* part_s= (float*)(smem + 37376);
  float* red_s = (float*)(smem + 38400);
  float* msg_s = (float*)(smem + 38432);
  float* u_s   = (float*)(smem + 38944);
  int*   idx_s = (int*)  (smem + 39456);

  const int tid  = threadIdx.x;
  const int blk  = blockIdx.x;          // = b*N + n
  const int bb   = blk >> 11;           // b  (N = 2048)
  const int lane = tid & 63;
  const int wave = tid >> 6;
  const int lr   = lane & 15;           // A-row / B-col / D-col within tile
  const int lq   = lane >> 4;           // quad

  // ---- pre-phase: node_i row (fp32) + neighbor indices ----
  if (tid < 128)      nhs[tid] = node_h[(size_t)blk * Cn + tid];
  else if (tid < 176) idx_s[tid - 128] = edge_index[blk * Kn + (tid - 128)];
  __syncthreads();

  // ---- stage X = [node_j | edge_h] as bf16, swizzled (stride 256 shorts) --
  for (int i = tid; i < 48 * 64; i += 256) {
    int r = i >> 6;
    int w = i & 63;            // 8-byte chunk index; c = w*4 shorts
    int c = w * 4;
    const float* src = (c < 128)
        ? node_h + (size_t)(bb * Nn + idx_s[r]) * Cn + c
        : edge_h + ((size_t)blk * Kn + r) * 128 + (c - 128);
    float4 v = *reinterpret_cast<const float4*>(src);
    union { short s[4]; unsigned long long u; } p;
    p.s[0] = f2bf(v.x); p.s[1] = f2bf(v.y);
    p.s[2] = f2bf(v.z); p.s[3] = f2bf(v.w);
    int addr = r * 256 + (((w >> 1) ^ (r & 7)) << 3) + (w & 1) * 4;
    *reinterpret_cast<unsigned long long*>(&Xs[addr]) = p.u;
  }

  // ---- node_i matvec partial: y_i[col] = sum_k nhs[k]*W1[k,col] ----
  {
    const int colv = tid & 127, half = tid >> 7;
    float a = 0.f;
    const int j0 = half * 64;
#pragma unroll 8
    for (int j = 0; j < 64; j++)
      a += nhs[j0 + j] * W1[(j0 + j) * 128 + colv];
    part_s[tid] = a;
  }
  __syncthreads();

  const short* W1p = wpack;           // 64 tiles (K=256)
  const short* W2p = wpack + 32768;   // 32 tiles
  const short* W3p = wpack + 49152;   // 32 tiles

  // ---------------- GEMM1: (48x256) @ W1[128:384] -> +y_i -> gelu -> H1s ---
  f32x4 acc[3][2] = {};
#pragma unroll
  for (int kt = 0; kt < 8; kt++) {
    bf16x8 bf0 = *reinterpret_cast<const bf16x8*>(W1p + ((kt * 8 + wave * 2 + 0) << 9) + lane * 8);
    bf16x8 bf1 = *reinterpret_cast<const bf16x8*>(W1p + ((kt * 8 + wave * 2 + 1) << 9) + lane * 8);
    int sw = (((kt * 4 + lq) ^ (lr & 7)) << 3);
    bf16x8 a0 = *reinterpret_cast<const bf16x8*>(&Xs[(0  + lr) * 256 + sw]);
    bf16x8 a1 = *reinterpret_cast<const bf16x8*>(&Xs[(16 + lr) * 256 + sw]);
    bf16x8 a2 = *reinterpret_cast<const bf16x8*>(&Xs[(32 + lr) * 256 + sw]);
    acc[0][0] = __builtin_amdgcn_mfma_f32_16x16x32_bf16(a0, bf0, acc[0][0], 0, 0, 0);
    acc[0][1] = __builtin_amdgcn_mfma_f32_16x16x32_bf16(a0, bf1, acc[0][1], 0, 0, 0);
    acc[1][0] = __builtin_amdgcn_mfma_f32_16x16x32_bf16(a1, bf0, acc[1][0], 0, 0, 0);
    acc[1][1] = __builtin_amdgcn_mfma_f32_16x16x32_bf16(a1, bf1, acc[1][1], 0, 0, 0);
    acc[2][0] = __builtin_amdgcn_mfma_f32_16x16x32_bf16(a2, bf0, acc[2][0], 0, 0, 0);
    acc[2][1] = __builtin_amdgcn_mfma_f32_16x16x32_bf16(a2, bf1, acc[2][1], 0, 0, 0);
  }
#pragma unroll
  for (int j = 0; j < 2; j++) {
    int col = (wave * 2 + j) * 16 + lr;
    float yi = part_s[col] + part_s[128 + col] + b1[col];
    int g = col >> 3, cl = col & 7;
#pragma unroll
    for (int mt = 0; mt < 3; mt++) {
#pragma unroll
      for (int r = 0; r < 4; r++) {
        int row = mt * 16 + lq * 4 + r;
        float gv = gelu_f(acc[mt][j][r] + yi);
        H1s[row * 128 + ((g ^ (row & 7)) << 3) + cl] = f2bf(gv);
      }
    }
  }
  __syncthreads();

  // ---------------- GEMM2: (48x128) @ W2 -> gelu -> H2s (overlays Xs) ------
  // (Xs reads all completed before the barrier above; H2s != H1s, so the
  //  epilogue can write H2s with no extra barrier before it.)
  f32x4 acc2[3][2] = {};
#pragma unroll
  for (int kt = 0; kt < 4; kt++) {
    bf16x8 bf0 = *reinterpret_cast<const bf16x8*>(W2p + ((kt * 8 + wave * 2 + 0) << 9) + lane * 8);
    bf16x8 bf1 = *reinterpret_cast<const bf16x8*>(W2p + ((kt * 8 + wave * 2 + 1) << 9) + lane * 8);
    int sw = (((kt * 4 + lq) ^ (lr & 7)) << 3);
    bf16x8 a0 = *reinterpret_cast<const bf16x8*>(&H1s[(0  + lr) * 128 + sw]);
    bf16x8 a1 = *reinterpret_cast<const bf16x8*>(&H1s[(16 + lr) * 128 + sw]);
    bf16x8 a2 = *reinterpret_cast<const bf16x8*>(&H1s[(32 + lr) * 128 + sw]);
    acc2[0][0] = __builtin_amdgcn_mfma_f32_16x16x32_bf16(a0, bf0, acc2[0][0], 0, 0, 0);
    acc2[0][1] = __builtin_amdgcn_mfma_f32_16x16x32_bf16(a0, bf1, acc2[0][1], 0, 0, 0);
    acc2[1][0] = __builtin_amdgcn_mfma_f32_16x16x32_bf16(a1, bf0, acc2[1][0], 0, 0, 0);
    acc2[1][1] = __builtin_amdgcn_mfma_f32_16x16x32_bf16(a1, bf1, acc2[1][1], 0, 0, 0);
    acc2[2][0] = __builtin_amdgcn_mfma_f32_16x16x32_bf16(a2, bf0, acc2[2][0], 0, 0, 0);
    acc2[2][1] = __builtin_amdgcn_mfma_f32_16x16x32_bf16(a2, bf1, acc2[2][1], 0, 0, 0);
  }
#pragma unroll
  for (int j = 0; j < 2; j++) {
    int col = (wave * 2 + j) * 16 + lr;
    float bias = b2[col];
    int g = col >> 3, cl = col & 7;
#pragma unroll
    for (int mt = 0; mt < 3; mt++) {
#pragma unroll
      for (int r = 0; r < 4; r++) {
        int row = mt * 16 + lq * 4 + r;
        float gv = gelu_f(acc2[mt][j][r] + bias);
        H2s[row * 128 + ((g ^ (row & 7)) << 3) + cl] = f2bf(gv);
      }
    }
  }
  __syncthreads();

  // ---------------- GEMM3: (48x128) @ W3, column-sum over 48 edges ---------
  f32x4 acc3[3][2] = {};
#pragma unroll
  for (int kt = 0; kt < 4; kt++) {
    bf16x8 bf0 = *reinterpret_cast<const bf16x8*>(W3p + ((kt * 8 + wave * 2 + 0) << 9) + lane * 8);
    bf16x8 bf1 = *reinterpret_cast<const bf16x8*>(W3p + ((kt * 8 + wave * 2 + 1) << 9) + lane * 8);
    int sw = (((kt * 4 + lq) ^ (lr & 7)) << 3);
    bf16x8 a0 = *reinterpret_cast<const bf16x8*>(&H2s[(0  + lr) * 128 + sw]);
    bf16x8 a1 = *reinterpret_cast<const bf16x8*>(&H2s[(16 + lr) * 128 + sw]);
    bf16x8 a2 = *reinterpret_cast<const bf16x8*>(&H2s[(32 + lr) * 128 + sw]);
    acc3[0][0] = __builtin_amdgcn_mfma_f32_16x16x32_bf16(a0, bf0, acc3[0][0], 0, 0, 0);
    acc3[0][1] = __builtin_amdgcn_mfma_f32_16x16x32_bf16(a0, bf1, acc3[0][1], 0, 0, 0);
    acc3[1][0] = __builtin_amdgcn_mfma_f32_16x16x32_bf16(a1, bf0, acc3[1][0], 0, 0, 0);
    acc3[1][1] = __builtin_amdgcn_mfma_f32_16x16x32_bf16(a1, bf1, acc3[1][1], 0, 0, 0);
    acc3[2][0] = __builtin_amdgcn_mfma_f32_16x16x32_bf16(a2, bf0, acc3[2][0], 0, 0, 0);
    acc3[2][1] = __builtin_amdgcn_mfma_f32_16x16x32_bf16(a2, bf1, acc3[2][1], 0, 0, 0);
  }
#pragma unroll
  for (int j = 0; j < 2; j++) {
    int col = (wave * 2 + j) * 16 + lr;
    float s = 0.f;
#pragma unroll
    for (int mt = 0; mt < 3; mt++)
#pragma unroll
      for (int r = 0; r < 4; r++) s += acc3[mt][j][r];
    s += __shfl_xor(s, 16);
    s += __shfl_xor(s, 32);
    if (lq == 0) msg_s[col] = (s + 48.0f * b3[col]) * (1.0f / 30.0f);
  }
  __syncthreads();

  // ---------------- LN -> u ; u@Wu+bu ; LN -> out --------------------------
  const int c    = tid & 127;
  const int half = tid >> 7;
  float nh = nhs[c];
  float x  = (half == 0) ? (nh + msg_s[c]) : 0.f;

  float sum, sumsq;
  block_reduce2(x, x * x, red_s, tid, sum, sumsq);
  float mu   = sum * (1.f / 128.f);
  float var  = sumsq * (1.f / 128.f) - mu * mu;
  float rstd = rsqrtf(var + 1e-5f);
  if (half == 0) u_s[c] = (x - mu) * rstd * ln_g[c] + ln_b[c];
  __syncthreads();

  {
    float a = 0.f;
    const int j0 = half * 64;
#pragma unroll 8
    for (int j = 0; j < 64; j++)
      a += u_s[j0 + j] * Wu[(j0 + j) * 128 + c];
    part_s[tid] = a;
  }
  __syncthreads();

  float y = (half == 0) ? (nh + part_s[c] + part_s[128 + c] + bu[c]) : 0.f;
  float sum2, sumsq2;
  block_reduce2(y, y * y, red_s, tid, sum2, sumsq2);
  float mu2   = sum2 * (1.f / 128.f);
  float var2  = sumsq2 * (1.f / 128.f) - mu2 * mu2;
  float rstd2 = rsqrtf(var2 + 1e-5f);
  if (half == 0)
    out[(size_t)blk * Cn + c] = (y - mu2) * rstd2 * ln_g[c] + ln_b[c];
}

extern "C" void kernel_launch(void* const* d_in, const int* in_sizes, int n_in,
                              void* d_out, int out_size, void* d_ws, size_t ws_size,
                              hipStream_t stream) {
  const float* node_h     = (const float*)d_in[0];
  const float* edge_h     = (const float*)d_in[1];
  const int*   edge_index = (const int*)  d_in[2];
  const float* W1 = (const float*)d_in[3];
  const float* b1 = (const float*)d_in[4];
  const float* W2 = (const float*)d_in[5];
  const float* b2 = (const float*)d_in[6];
  const float* W3 = (const float*)d_in[7];
  const float* b3 = (const float*)d_in[8];
  const float* Wu = (const float*)d_in[9];
  const float* bu = (const float*)d_in[10];
  const float* ln_g = (const float*)d_in[11];
  const float* ln_b = (const float*)d_in[12];
  float* out   = (float*)d_out;
  short* wpack = (short*)d_ws;   // 128 KiB

  pack_weights<<<32, 256, 0, stream>>>(W1, W2, W3, wpack);
  node_update_kernel<<<Bn * Nn, 256, 0, stream>>>(
      node_h, edge_h, edge_index, wpack,
      W1, b1, b2, b3, Wu, bu, ln_g, ln_b, out);
}

// Round 3
// 215.378 us; speedup vs baseline: 1.4310x; 1.1684x over previous
//
#include <hip/hip_runtime.h>
#include <hip/hip_bf16.h>
#include <math.h>

// Problem constants
#define Bn   2
#define Nn   2048
#define Kn   48
#define Cn   128

typedef short bf16x8 __attribute__((ext_vector_type(8)));
typedef float f32x4  __attribute__((ext_vector_type(4)));

#if __has_builtin(__builtin_amdgcn_cvt_pk_bf16_f32)
#define HAS_PK 1
#endif

__device__ __forceinline__ short f2bf(float f) {
  union { float f; unsigned u; } v; v.f = f;
  unsigned r = v.u + 0x7fffu + ((v.u >> 16) & 1u);
  return (short)(r >> 16);
}

// pack 2 fp32 -> packed bf16x2 in one dword (v_cvt_pk_bf16_f32 when available)
__device__ __forceinline__ unsigned pk2(float a, float b) {
#ifdef HAS_PK
  auto p = __builtin_amdgcn_cvt_pk_bf16_f32(a, b);
  return __builtin_bit_cast(unsigned, p);
#else
  return (unsigned)(unsigned short)f2bf(a) | ((unsigned)(unsigned short)f2bf(b) << 16);
#endif
}

// tanh-GELU with exp2-folded constants; ~7 VALU. |err| vs erf-gelu ~3e-4.
__device__ __forceinline__ float gelu_f(float x) {
  float z = x * (-2.3021991f - 0.10294200f * x * x);   // = -log2(e)*1.5958*(1+0.0447x^2)
  float e = __builtin_amdgcn_exp2f(z);
  return x * __builtin_amdgcn_rcpf(1.0f + e);
}

// ---------------------------------------------------------------------------
// Pack all weights into bf16 MFMA B-fragment tiles (512 shorts each; lane l
// holds 8 bf16 = W[kt*32 + (l>>4)*8 + j][nt*16 + (l&15)]).
// ws layout (shorts): W1i(rows0-127) [0,16384) | W1e(rows128-383) [16384,49152)
//                     W2 [49152,65536) | W3 [65536,81920) | Wu [81920,98304)
// ---------------------------------------------------------------------------
__global__ void pack_weights(const float* __restrict__ W1,
                             const float* __restrict__ W2,
                             const float* __restrict__ W3,
                             const float* __restrict__ Wu,
                             short* __restrict__ ws) {
  int tid = blockIdx.x * blockDim.x + threadIdx.x;
  if (tid >= 192 * 64) return;
  int lane = tid & 63;
  int tile = tid >> 6;
  const float* W; short* dst;
  if (tile < 32)       { W = W1;               dst = ws; }
  else if (tile < 96)  { W = W1 + 16384;       dst = ws + 16384; tile -= 32; }
  else if (tile < 128) { W = W2;               dst = ws + 49152; tile -= 96; }
  else if (tile < 160) { W = W3;               dst = ws + 65536; tile -= 128; }
  else                 { W = Wu;               dst = ws + 81920; tile -= 160; }
  int kt = tile >> 3, nt = tile & 7;
  int n  = nt * 16 + (lane & 15);
  int k0 = kt * 32 + (lane >> 4) * 8;
  union { short s[8]; bf16x8 v; } u8;
#pragma unroll
  for (int j = 0; j < 8; j++) u8.s[j] = f2bf(W[(k0 + j) * 128 + n]);
  *reinterpret_cast<bf16x8*>(dst + (tile << 9) + lane * 8) = u8.v;
}

// Block reduction of two values across 256 threads (all threads must call).
__device__ __forceinline__ void block_reduce2(float v1, float v2, float* red,
                                              int tid, float& o1, float& o2) {
#pragma unroll
  for (int off = 32; off >= 1; off >>= 1) {
    v1 += __shfl_xor(v1, off);
    v2 += __shfl_xor(v2, off);
  }
  if ((tid & 63) == 0) { red[tid >> 6] = v1; red[4 + (tid >> 6)] = v2; }
  __syncthreads();
  o1 = red[0] + red[1] + red[2] + red[3];
  o2 = red[4] + red[5] + red[6] + red[7];
  __syncthreads();
}

// ---------------------------------------------------------------------------
// One block per node. 256 threads = 4 waves; wave w owns cols [w*32,w*32+32).
// All 1x128 matvecs (node_i@W1[0:128], h2sum@W3, u@Wu) are row-vector MFMAs.
// LDS rows XOR-swizzled on 16B granules (stride multiple of 32 dwords).
// ---------------------------------------------------------------------------
__global__ __launch_bounds__(256, 6)
void node_update_kernel(const float* __restrict__ node_h,
                        const float* __restrict__ edge_h,
                        const int*   __restrict__ edge_index,
                        const short* __restrict__ wpack,
                        const float* __restrict__ b1,
                        const float* __restrict__ b2,
                        const float* __restrict__ b3,
                        const float* __restrict__ bu,
                        const float* __restrict__ ln_g,
                        const float* __restrict__ ln_b,
                        float* __restrict__ out) {
  // LDS (bytes), 26592 total -> 6 blocks/CU:
  //  [0,24576)      Xs 48x256 bf16 swizzled (node_j|edge_h); dead after GEMM1
  //  [12288,24576)  H1s 48x128 bf16 swizzled (overlays Xs; written post-barrier)
  //  [24576,24832)  nhb: node_i bf16 x128
  //  [24832,25344)  nhs: node_i f32 x128
  //  [25344,25536)  idx_s x48
  //  [25536,26048)  msg_s f32 x128 (reused as upd_s)
  //  [26048,26304)  hsb: h2 col-sums bf16 x128
  //  [26304,26560)  ub: LN1 output bf16 x128
  //  [26560,26592)  red_s f32 x8
  __shared__ __align__(16) char smem[26592];
  short* Xs    = (short*)smem;
  short* H1s   = (short*)(smem + 12288);
  short* nhb   = (short*)(smem + 24576);
  float* nhs   = (float*)(smem + 24832);
  int*   idx_s = (int*)  (smem + 25344);
  float* msg_s = (float*)(smem + 25536);
  short* hsb   = (short*)(smem + 26048);
  short* ub    = (short*)(smem + 26304);
  float* red_s = (float*)(smem + 26560);

  const int tid  = threadIdx.x;
  const int blk  = blockIdx.x;
  const int bb   = blk >> 11;
  const int lane = tid & 63;
  const int wave = tid >> 6;
  const int lr   = lane & 15;
  const int lq   = lane >> 4;

  const short* W1i = wpack;
  const short* W1e = wpack + 16384;
  const short* W2p = wpack + 49152;
  const short* W3p = wpack + 65536;
  const short* Wup = wpack + 81920;

  // ---- phase 0: node_i (f32 + bf16) and neighbor indices ----
  if (tid < 128) {
    float v = node_h[(size_t)blk * Cn + tid];
    nhs[tid] = v;
    nhb[tid] = f2bf(v);
  } else if (tid < 176) {
    idx_s[tid - 128] = edge_index[blk * Kn + (tid - 128)];
  }
  __syncthreads();

  // ---- stage X = [node_j | edge_h] bf16 swizzled (6 iters, 32B/lane) ----
#pragma unroll
  for (int i = tid; i < 48 * 32; i += 256) {
    int r = i >> 5;
    int w = i & 31;                  // 16B output granule = 8 input floats
    const float* src = (w < 16)
        ? node_h + (size_t)(bb * Nn + idx_s[r]) * Cn + w * 8
        : edge_h + ((size_t)blk * Kn + r) * Cn + (w - 16) * 8;
    float4 v0 = *reinterpret_cast<const float4*>(src);
    float4 v1 = *reinterpret_cast<const float4*>(src + 4);
    uint4 p;
    p.x = pk2(v0.x, v0.y); p.y = pk2(v0.z, v0.w);
    p.z = pk2(v1.x, v1.y); p.w = pk2(v1.z, v1.w);
    *reinterpret_cast<uint4*>(&Xs[r * 256 + ((w ^ (r & 7)) << 3)]) = p;
  }

  // ---- node_i row-vector MFMA: yi[col] = node_i @ W1[0:128] --------------
  f32x4 accY[2] = {};
#pragma unroll
  for (int kt = 0; kt < 4; kt++) {
    bf16x8 av = {};
    if (lr == 0) av = *reinterpret_cast<const bf16x8*>(&nhb[kt * 32 + lq * 8]);
    bf16x8 bv0 = *reinterpret_cast<const bf16x8*>(W1i + ((kt * 8 + wave * 2 + 0) << 9) + lane * 8);
    bf16x8 bv1 = *reinterpret_cast<const bf16x8*>(W1i + ((kt * 8 + wave * 2 + 1) << 9) + lane * 8);
    accY[0] = __builtin_amdgcn_mfma_f32_16x16x32_bf16(av, bv0, accY[0], 0, 0, 0);
    accY[1] = __builtin_amdgcn_mfma_f32_16x16x32_bf16(av, bv1, accY[1], 0, 0, 0);
  }
  __syncthreads();

  // ---- GEMM1: (48x256) @ W1[128:384] ----
  f32x4 acc[3][2] = {};
#pragma unroll
  for (int kt = 0; kt < 8; kt++) {
    bf16x8 bf0 = *reinterpret_cast<const bf16x8*>(W1e + ((kt * 8 + wave * 2 + 0) << 9) + lane * 8);
    bf16x8 bf1 = *reinterpret_cast<const bf16x8*>(W1e + ((kt * 8 + wave * 2 + 1) << 9) + lane * 8);
    int sw = (((kt * 4 + lq) ^ (lr & 7)) << 3);
    bf16x8 a0 = *reinterpret_cast<const bf16x8*>(&Xs[(0  + lr) * 256 + sw]);
    bf16x8 a1 = *reinterpret_cast<const bf16x8*>(&Xs[(16 + lr) * 256 + sw]);
    bf16x8 a2 = *reinterpret_cast<const bf16x8*>(&Xs[(32 + lr) * 256 + sw]);
    acc[0][0] = __builtin_amdgcn_mfma_f32_16x16x32_bf16(a0, bf0, acc[0][0], 0, 0, 0);
    acc[0][1] = __builtin_amdgcn_mfma_f32_16x16x32_bf16(a0, bf1, acc[0][1], 0, 0, 0);
    acc[1][0] = __builtin_amdgcn_mfma_f32_16x16x32_bf16(a1, bf0, acc[1][0], 0, 0, 0);
    acc[1][1] = __builtin_amdgcn_mfma_f32_16x16x32_bf16(a1, bf1, acc[1][1], 0, 0, 0);
    acc[2][0] = __builtin_amdgcn_mfma_f32_16x16x32_bf16(a2, bf0, acc[2][0], 0, 0, 0);
    acc[2][1] = __builtin_amdgcn_mfma_f32_16x16x32_bf16(a2, bf1, acc[2][1], 0, 0, 0);
  }
  __syncthreads();   // all Xs reads done before H1s (overlay) writes

  // ---- GEMM1 epilogue: +yi +b1, gelu, bf16 -> H1s ----
#pragma unroll
  for (int j = 0; j < 2; j++) {
    int col = (wave * 2 + j) * 16 + lr;
    float yi = __shfl(accY[j][0], lr) + b1[col];
    int g = col >> 3, cl = col & 7;
#pragma unroll
    for (int mt = 0; mt < 3; mt++) {
      int r0 = mt * 16 + lq * 4;
      float g0 = gelu_f(acc[mt][j][0] + yi);
      float g1 = gelu_f(acc[mt][j][1] + yi);
      float g2 = gelu_f(acc[mt][j][2] + yi);
      float g3 = gelu_f(acc[mt][j][3] + yi);
      unsigned p01 = pk2(g0, g1), p23 = pk2(g2, g3);
      H1s[(r0 + 0) * 128 + ((g ^ ((r0 + 0) & 7)) << 3) + cl] = (short)(p01 & 0xffff);
      H1s[(r0 + 1) * 128 + ((g ^ ((r0 + 1) & 7)) << 3) + cl] = (short)(p01 >> 16);
      H1s[(r0 + 2) * 128 + ((g ^ ((r0 + 2) & 7)) << 3) + cl] = (short)(p23 & 0xffff);
      H1s[(r0 + 3) * 128 + ((g ^ ((r0 + 3) & 7)) << 3) + cl] = (short)(p23 >> 16);
    }
  }
  __syncthreads();

  // ---- GEMM2: (48x128) @ W2, fused gelu + column-sum over 48 edges ----
  f32x4 acc2[3][2] = {};
#pragma unroll
  for (int kt = 0; kt < 4; kt++) {
    bf16x8 bf0 = *reinterpret_cast<const bf16x8*>(W2p + ((kt * 8 + wave * 2 + 0) << 9) + lane * 8);
    bf16x8 bf1 = *reinterpret_cast<const bf16x8*>(W2p + ((kt * 8 + wave * 2 + 1) << 9) + lane * 8);
    int sw = (((kt * 4 + lq) ^ (lr & 7)) << 3);
    bf16x8 a0 = *reinterpret_cast<const bf16x8*>(&H1s[(0  + lr) * 128 + sw]);
    bf16x8 a1 = *reinterpret_cast<const bf16x8*>(&H1s[(16 + lr) * 128 + sw]);
    bf16x8 a2 = *reinterpret_cast<const bf16x8*>(&H1s[(32 + lr) * 128 + sw]);
    acc2[0][0] = __builtin_amdgcn_mfma_f32_16x16x32_bf16(a0, bf0, acc2[0][0], 0, 0, 0);
    acc2[0][1] = __builtin_amdgcn_mfma_f32_16x16x32_bf16(a0, bf1, acc2[0][1], 0, 0, 0);
    acc2[1][0] = __builtin_amdgcn_mfma_f32_16x16x32_bf16(a1, bf0, acc2[1][0], 0, 0, 0);
    acc2[1][1] = __builtin_amdgcn_mfma_f32_16x16x32_bf16(a1, bf1, acc2[1][1], 0, 0, 0);
    acc2[2][0] = __builtin_amdgcn_mfma_f32_16x16x32_bf16(a2, bf0, acc2[2][0], 0, 0, 0);
    acc2[2][1] = __builtin_amdgcn_mfma_f32_16x16x32_bf16(a2, bf1, acc2[2][1], 0, 0, 0);
  }
#pragma unroll
  for (int j = 0; j < 2; j++) {
    int col = (wave * 2 + j) * 16 + lr;
    float bias = b2[col];
    float s = 0.f;
#pragma unroll
    for (int mt = 0; mt < 3; mt++)
#pragma unroll
      for (int r = 0; r < 4; r++) s += gelu_f(acc2[mt][j][r] + bias);
    s += __shfl_xor(s, 16);
    s += __shfl_xor(s, 32);
    if (lq == 0) hsb[col] = f2bf(s);   // fp32 sum of 48 gelus, rounded once
  }
  __syncthreads();

  // ---- msg row-vector MFMA: msg = (h2sum @ W3 + 48*b3) / 30 ----
  f32x4 accM[2] = {};
#pragma unroll
  for (int kt = 0; kt < 4; kt++) {
    bf16x8 av = {};
    if (lr == 0) av = *reinterpret_cast<const bf16x8*>(&hsb[kt * 32 + lq * 8]);
    bf16x8 bv0 = *reinterpret_cast<const bf16x8*>(W3p + ((kt * 8 + wave * 2 + 0) << 9) + lane * 8);
    bf16x8 bv1 = *reinterpret_cast<const bf16x8*>(W3p + ((kt * 8 + wave * 2 + 1) << 9) + lane * 8);
    accM[0] = __builtin_amdgcn_mfma_f32_16x16x32_bf16(av, bv0, accM[0], 0, 0, 0);
    accM[1] = __builtin_amdgcn_mfma_f32_16x16x32_bf16(av, bv1, accM[1], 0, 0, 0);
  }
  if (lq == 0) {
#pragma unroll
    for (int j = 0; j < 2; j++) {
      int col = (wave * 2 + j) * 16 + lr;
      msg_s[col] = (accM[j][0] + 48.0f * b3[col]) * (1.0f / 30.0f);
    }
  }
  __syncthreads();

  // ---- LN1 -> u (bf16) ----
  const int c    = tid & 127;
  const int half = tid >> 7;
  float nh = nhs[c];
  float x  = (half == 0) ? (nh + msg_s[c]) : 0.f;
  float sum, sumsq;
  block_reduce2(x, x * x, red_s, tid, sum, sumsq);
  float mu   = sum * (1.f / 128.f);
  float var  = sumsq * (1.f / 128.f) - mu * mu;
  float rstd = rsqrtf(var + 1e-5f);
  if (half == 0) ub[c] = f2bf((x - mu) * rstd * ln_g[c] + ln_b[c]);
  __syncthreads();

  // ---- node-update row-vector MFMA: upd = u @ Wu + bu (reuses msg_s) ----
  f32x4 accU[2] = {};
#pragma unroll
  for (int kt = 0; kt < 4; kt++) {
    bf16x8 av = {};
    if (lr == 0) av = *reinterpret_cast<const bf16x8*>(&ub[kt * 32 + lq * 8]);
    bf16x8 bv0 = *reinterpret_cast<const bf16x8*>(Wup + ((kt * 8 + wave * 2 + 0) << 9) + lane * 8);
    bf16x8 bv1 = *reinterpret_cast<const bf16x8*>(Wup + ((kt * 8 + wave * 2 + 1) << 9) + lane * 8);
    accU[0] = __builtin_amdgcn_mfma_f32_16x16x32_bf16(av, bv0, accU[0], 0, 0, 0);
    accU[1] = __builtin_amdgcn_mfma_f32_16x16x32_bf16(av, bv1, accU[1], 0, 0, 0);
  }
  if (lq == 0) {
#pragma unroll
    for (int j = 0; j < 2; j++) {
      int col = (wave * 2 + j) * 16 + lr;
      msg_s[col] = accU[j][0] + bu[col];
    }
  }
  __syncthreads();

  // ---- LN2 -> out ----
  float y = (half == 0) ? (nh + msg_s[c]) : 0.f;
  float sum2, sumsq2;
  block_reduce2(y, y * y, red_s, tid, sum2, sumsq2);
  float mu2   = sum2 * (1.f / 128.f);
  float var2  = sumsq2 * (1.f / 128.f) - mu2 * mu2;
  float rstd2 = rsqrtf(var2 + 1e-5f);
  if (half == 0)
    out[(size_t)blk * Cn + c] = (y - mu2) * rstd2 * ln_g[c] + ln_b[c];
}

extern "C" void kernel_launch(void* const* d_in, const int* in_sizes, int n_in,
                              void* d_out, int out_size, void* d_ws, size_t ws_size,
                              hipStream_t stream) {
  const float* node_h     = (const float*)d_in[0];
  const float* edge_h     = (const float*)d_in[1];
  const int*   edge_index = (const int*)  d_in[2];
  const float* W1 = (const float*)d_in[3];
  const float* b1 = (const float*)d_in[4];
  const float* W2 = (const float*)d_in[5];
  const float* b2 = (const float*)d_in[6];
  const float* W3 = (const float*)d_in[7];
  const float* b3 = (const float*)d_in[8];
  const float* Wu = (const float*)d_in[9];
  const float* bu = (const float*)d_in[10];
  const float* ln_g = (const float*)d_in[11];
  const float* ln_b = (const float*)d_in[12];
  float* out   = (float*)d_out;
  short* wpack = (short*)d_ws;   // 192 KiB

  pack_weights<<<48, 256, 0, stream>>>(W1, W2, W3, Wu, wpack);
  node_update_kernel<<<Bn * Nn, 256, 0, stream>>>(
      node_h, edge_h, edge_index, wpack,
      b1, b2, b3, bu, ln_g, ln_b, out);
}

// Round 4
// 204.618 us; speedup vs baseline: 1.5063x; 1.0526x over previous
//
#include <hip/hip_runtime.h>
#include <hip/hip_bf16.h>
#include <math.h>

// Problem constants
#define Bn   2
#define Nn   2048
#define Kn   48
#define Cn   128
#define G2   16     // nodes per block in the tail kernel

typedef short bf16x8 __attribute__((ext_vector_type(8)));
typedef float f32x4  __attribute__((ext_vector_type(4)));

#if __has_builtin(__builtin_amdgcn_cvt_pk_bf16_f32)
#define HAS_PK 1
#endif

__device__ __forceinline__ short f2bf(float f) {
  union { float f; unsigned u; } v; v.f = f;
  unsigned r = v.u + 0x7fffu + ((v.u >> 16) & 1u);
  return (short)(r >> 16);
}

__device__ __forceinline__ unsigned pk2(float a, float b) {
#ifdef HAS_PK
  auto p = __builtin_amdgcn_cvt_pk_bf16_f32(a, b);
  return __builtin_bit_cast(unsigned, p);
#else
  return (unsigned)(unsigned short)f2bf(a) | ((unsigned)(unsigned short)f2bf(b) << 16);
#endif
}

// tanh-GELU with exp2-folded constants; |err| vs erf-gelu ~3e-4.
__device__ __forceinline__ float gelu_f(float x) {
  float z = x * (-2.3021991f - 0.10294200f * x * x);
  float e = __builtin_amdgcn_exp2f(z);
  return x * __builtin_amdgcn_rcpf(1.0f + e);
}

// ---------------------------------------------------------------------------
// Pack weights into bf16 MFMA B-fragment tiles (512 shorts each; lane l holds
// 8 bf16 = W[kt*32 + (l>>4)*8 + j][nt*16 + (l&15)]).
// ws (shorts): W1i [0,16384) | W1e [16384,49152) | W2 [49152,65536)
//              W3 [65536,81920) | Wu [81920,98304)
// ---------------------------------------------------------------------------
__global__ void pack_weights(const float* __restrict__ W1,
                             const float* __restrict__ W2,
                             const float* __restrict__ W3,
                             const float* __restrict__ Wu,
                             short* __restrict__ ws) {
  int tid = blockIdx.x * blockDim.x + threadIdx.x;
  if (tid >= 192 * 64) return;
  int lane = tid & 63;
  int tile = tid >> 6;
  const float* W; short* dst;
  if (tile < 32)       { W = W1;         dst = ws; }
  else if (tile < 96)  { W = W1 + 16384; dst = ws + 16384; tile -= 32; }
  else if (tile < 128) { W = W2;         dst = ws + 49152; tile -= 96; }
  else if (tile < 160) { W = W3;         dst = ws + 65536; tile -= 128; }
  else                 { W = Wu;         dst = ws + 81920; tile -= 160; }
  int kt = tile >> 3, nt = tile & 7;
  int n  = nt * 16 + (lane & 15);
  int k0 = kt * 32 + (lane >> 4) * 8;
  union { short s[8]; bf16x8 v; } u8;
#pragma unroll
  for (int j = 0; j < 8; j++) u8.s[j] = f2bf(W[(k0 + j) * 128 + n]);
  *reinterpret_cast<bf16x8*>(dst + (tile << 9) + lane * 8) = u8.v;
}

// ---------------------------------------------------------------------------
// Kernel 1: per-node edge MLP. One block per node; 256 thr = 4 waves; wave w
// owns cols [w*32,w*32+32). Ends writing hs[node][128] (f32 col-sums of
// gelu(h2)) into the out buffer (scratch; kernel2 consumes then overwrites).
// LDS rows XOR-swizzled on 16B granules (stride multiple of 32 dwords).
// ---------------------------------------------------------------------------
__global__ __launch_bounds__(256, 6)
void node_update_kernel(const float* __restrict__ node_h,
                        const float* __restrict__ edge_h,
                        const int*   __restrict__ edge_index,
                        const short* __restrict__ wpack,
                        const float* __restrict__ b1,
                        const float* __restrict__ b2,
                        float* __restrict__ hs_out) {
  // LDS (bytes), 25024 total:
  //  [0,24576)      Xs 48x256 bf16 swizzled (node_j|edge_h); dead after GEMM1
  //  [12288,24576)  H1s 48x128 bf16 swizzled (overlays Xs; written post-barrier)
  //  [24576,24832)  nhb: node_i bf16 x128
  //  [24832,25024)  idx_s x48
  __shared__ __align__(16) char smem[25024];
  short* Xs    = (short*)smem;
  short* H1s   = (short*)(smem + 12288);
  short* nhb   = (short*)(smem + 24576);
  int*   idx_s = (int*)  (smem + 24832);

  const int tid  = threadIdx.x;
  const int blk  = blockIdx.x;
  const int bb   = blk >> 11;
  const int lane = tid & 63;
  const int wave = tid >> 6;
  const int lr   = lane & 15;
  const int lq   = lane >> 4;

  const short* W1i = wpack;
  const short* W1e = wpack + 16384;
  const short* W2p = wpack + 49152;

  // ---- phase 0: node_i bf16 + neighbor indices ----
  if (tid < 128) {
    nhb[tid] = f2bf(node_h[(size_t)blk * Cn + tid]);
  } else if (tid < 176) {
    idx_s[tid - 128] = edge_index[blk * Kn + (tid - 128)];
  }
  __syncthreads();

  // ---- stage X = [node_j | edge_h] bf16 swizzled (w uniform per thread) ----
  {
    const int w  = tid & 31;   // 16B granule within row (0..15 node, 16..31 edge)
    const int rr = tid >> 5;   // 0..7
#pragma unroll
    for (int k = 0; k < 6; k++) {
      int r = rr + k * 8;
      const float* src = (w < 16)
          ? node_h + (size_t)(bb * Nn + idx_s[r]) * Cn + w * 8
          : edge_h + ((size_t)blk * Kn + r) * Cn + (w - 16) * 8;
      float4 v0 = *reinterpret_cast<const float4*>(src);
      float4 v1 = *reinterpret_cast<const float4*>(src + 4);
      uint4 p;
      p.x = pk2(v0.x, v0.y); p.y = pk2(v0.z, v0.w);
      p.z = pk2(v1.x, v1.y); p.w = pk2(v1.z, v1.w);
      *reinterpret_cast<uint4*>(&Xs[r * 256 + ((w ^ (r & 7)) << 3)]) = p;
    }
  }

  // ---- node_i row-vector MFMA (overlaps staging latency) ----
  f32x4 accY[2] = {};
#pragma unroll
  for (int kt = 0; kt < 4; kt++) {
    bf16x8 av = {};
    if (lr == 0) av = *reinterpret_cast<const bf16x8*>(&nhb[kt * 32 + lq * 8]);
    bf16x8 bv0 = *reinterpret_cast<const bf16x8*>(W1i + ((kt * 8 + wave * 2 + 0) << 9) + lane * 8);
    bf16x8 bv1 = *reinterpret_cast<const bf16x8*>(W1i + ((kt * 8 + wave * 2 + 1) << 9) + lane * 8);
    accY[0] = __builtin_amdgcn_mfma_f32_16x16x32_bf16(av, bv0, accY[0], 0, 0, 0);
    accY[1] = __builtin_amdgcn_mfma_f32_16x16x32_bf16(av, bv1, accY[1], 0, 0, 0);
  }
  __syncthreads();

  // ---- GEMM1: (48x256) @ W1[128:384] ----
  f32x4 acc[3][2] = {};
#pragma unroll
  for (int kt = 0; kt < 8; kt++) {
    bf16x8 bf0 = *reinterpret_cast<const bf16x8*>(W1e + ((kt * 8 + wave * 2 + 0) << 9) + lane * 8);
    bf16x8 bf1 = *reinterpret_cast<const bf16x8*>(W1e + ((kt * 8 + wave * 2 + 1) << 9) + lane * 8);
    int sw = (((kt * 4 + lq) ^ (lr & 7)) << 3);
    bf16x8 a0 = *reinterpret_cast<const bf16x8*>(&Xs[(0  + lr) * 256 + sw]);
    bf16x8 a1 = *reinterpret_cast<const bf16x8*>(&Xs[(16 + lr) * 256 + sw]);
    bf16x8 a2 = *reinterpret_cast<const bf16x8*>(&Xs[(32 + lr) * 256 + sw]);
    acc[0][0] = __builtin_amdgcn_mfma_f32_16x16x32_bf16(a0, bf0, acc[0][0], 0, 0, 0);
    acc[0][1] = __builtin_amdgcn_mfma_f32_16x16x32_bf16(a0, bf1, acc[0][1], 0, 0, 0);
    acc[1][0] = __builtin_amdgcn_mfma_f32_16x16x32_bf16(a1, bf0, acc[1][0], 0, 0, 0);
    acc[1][1] = __builtin_amdgcn_mfma_f32_16x16x32_bf16(a1, bf1, acc[1][1], 0, 0, 0);
    acc[2][0] = __builtin_amdgcn_mfma_f32_16x16x32_bf16(a2, bf0, acc[2][0], 0, 0, 0);
    acc[2][1] = __builtin_amdgcn_mfma_f32_16x16x32_bf16(a2, bf1, acc[2][1], 0, 0, 0);
  }
  __syncthreads();   // all Xs reads done before H1s (overlay) writes

  // ---- GEMM1 epilogue: +yi +b1, gelu, bf16 -> H1s ----
#pragma unroll
  for (int j = 0; j < 2; j++) {
    int col = (wave * 2 + j) * 16 + lr;
    float yi = __shfl(accY[j][0], lr) + b1[col];
    int g = col >> 3, cl = col & 7;
#pragma unroll
    for (int mt = 0; mt < 3; mt++) {
      int r0 = mt * 16 + lq * 4;
      float g0 = gelu_f(acc[mt][j][0] + yi);
      float g1 = gelu_f(acc[mt][j][1] + yi);
      float g2 = gelu_f(acc[mt][j][2] + yi);
      float g3 = gelu_f(acc[mt][j][3] + yi);
      unsigned p01 = pk2(g0, g1), p23 = pk2(g2, g3);
      H1s[(r0 + 0) * 128 + ((g ^ ((r0 + 0) & 7)) << 3) + cl] = (short)(p01 & 0xffff);
      H1s[(r0 + 1) * 128 + ((g ^ ((r0 + 1) & 7)) << 3) + cl] = (short)(p01 >> 16);
      H1s[(r0 + 2) * 128 + ((g ^ ((r0 + 2) & 7)) << 3) + cl] = (short)(p23 & 0xffff);
      H1s[(r0 + 3) * 128 + ((g ^ ((r0 + 3) & 7)) << 3) + cl] = (short)(p23 >> 16);
    }
  }
  __syncthreads();

  // ---- GEMM2: (48x128) @ W2, fused gelu + column-sum; write hs f32 ----
  f32x4 acc2[3][2] = {};
#pragma unroll
  for (int kt = 0; kt < 4; kt++) {
    bf16x8 bf0 = *reinterpret_cast<const bf16x8*>(W2p + ((kt * 8 + wave * 2 + 0) << 9) + lane * 8);
    bf16x8 bf1 = *reinterpret_cast<const bf16x8*>(W2p + ((kt * 8 + wave * 2 + 1) << 9) + lane * 8);
    int sw = (((kt * 4 + lq) ^ (lr & 7)) << 3);
    bf16x8 a0 = *reinterpret_cast<const bf16x8*>(&H1s[(0  + lr) * 128 + sw]);
    bf16x8 a1 = *reinterpret_cast<const bf16x8*>(&H1s[(16 + lr) * 128 + sw]);
    bf16x8 a2 = *reinterpret_cast<const bf16x8*>(&H1s[(32 + lr) * 128 + sw]);
    acc2[0][0] = __builtin_amdgcn_mfma_f32_16x16x32_bf16(a0, bf0, acc2[0][0], 0, 0, 0);
    acc2[0][1] = __builtin_amdgcn_mfma_f32_16x16x32_bf16(a0, bf1, acc2[0][1], 0, 0, 0);
    acc2[1][0] = __builtin_amdgcn_mfma_f32_16x16x32_bf16(a1, bf0, acc2[1][0], 0, 0, 0);
    acc2[1][1] = __builtin_amdgcn_mfma_f32_16x16x32_bf16(a1, bf1, acc2[1][1], 0, 0, 0);
    acc2[2][0] = __builtin_amdgcn_mfma_f32_16x16x32_bf16(a2, bf0, acc2[2][0], 0, 0, 0);
    acc2[2][1] = __builtin_amdgcn_mfma_f32_16x16x32_bf16(a2, bf1, acc2[2][1], 0, 0, 0);
  }
#pragma unroll
  for (int j = 0; j < 2; j++) {
    int col = (wave * 2 + j) * 16 + lr;
    float bias = b2[col];
    float s = 0.f;
#pragma unroll
    for (int mt = 0; mt < 3; mt++)
#pragma unroll
      for (int r = 0; r < 4; r++) s += gelu_f(acc2[mt][j][r] + bias);
    s += __shfl_xor(s, 16);
    s += __shfl_xor(s, 32);
    if (lq == 0) hs_out[(size_t)blk * Cn + col] = s;
  }
}

// ---------------------------------------------------------------------------
// Kernel 2 (tail, batched): 16 nodes per block.
// msg = (hs @ W3 + 48*b3)/30 ; x = nh + msg ; u = LN(x) ;
// y = nh + u@Wu + bu ; out = LN(y).  Matvecs are dense M=16 MFMA GEMMs.
// Reads hs from the out buffer, overwrites the same rows at the end.
// ---------------------------------------------------------------------------
__global__ __launch_bounds__(256, 4)
void tail_kernel(const float* __restrict__ node_h,
                 const short* __restrict__ wpack,
                 const float* __restrict__ b3,
                 const float* __restrict__ bu,
                 const float* __restrict__ ln_g,
                 const float* __restrict__ ln_b,
                 float* __restrict__ out) {
  // LDS: hsB 16x128 bf16 swz [0,4096) | nhr 16x128 f32 [4096,12288)
  //      xs 16x132 f32 [12288,20736) | usB 16x128 bf16 swz [20736,24832)
  __shared__ __align__(16) char sm2[24832];
  short* hsB = (short*)sm2;
  float* nhr = (float*)(sm2 + 4096);
  float* xs  = (float*)(sm2 + 12288);
  short* usB = (short*)(sm2 + 20736);

  const int tid  = threadIdx.x;
  const int lane = tid & 63;
  const int wave = tid >> 6;
  const int lr   = lane & 15;
  const int lq   = lane >> 4;
  const int n0   = blockIdx.x * G2;

  const short* W3p = wpack + 65536;
  const short* Wup = wpack + 81920;

  // ---- stage node_h (f32) and hs (bf16, swizzled) ----
  {
    int row = tid >> 4, seg = tid & 15;
    const float* p = node_h + (size_t)(n0 + row) * Cn + seg * 8;
    float4 a0 = *reinterpret_cast<const float4*>(p);
    float4 a1 = *reinterpret_cast<const float4*>(p + 4);
    *reinterpret_cast<float4*>(&nhr[row * 128 + seg * 8])     = a0;
    *reinterpret_cast<float4*>(&nhr[row * 128 + seg * 8 + 4]) = a1;
    const float* q = out + (size_t)(n0 + row) * Cn + seg * 8;  // hs scratch
    float4 c0 = *reinterpret_cast<const float4*>(q);
    float4 c1 = *reinterpret_cast<const float4*>(q + 4);
    uint4 pk;
    pk.x = pk2(c0.x, c0.y); pk.y = pk2(c0.z, c0.w);
    pk.z = pk2(c1.x, c1.y); pk.w = pk2(c1.z, c1.w);
    *reinterpret_cast<uint4*>(&hsB[row * 128 + ((seg ^ (row & 7)) << 3)]) = pk;
  }
  __syncthreads();

  // ---- msg GEMM (M=16): hs @ W3 ; x = nh + (.+48*b3)/30 -> xs ----
  f32x4 am[2] = {};
#pragma unroll
  for (int kt = 0; kt < 4; kt++) {
    bf16x8 av = *reinterpret_cast<const bf16x8*>(&hsB[lr * 128 + (((kt * 4 + lq) ^ (lr & 7)) << 3)]);
    bf16x8 bv0 = *reinterpret_cast<const bf16x8*>(W3p + ((kt * 8 + wave * 2 + 0) << 9) + lane * 8);
    bf16x8 bv1 = *reinterpret_cast<const bf16x8*>(W3p + ((kt * 8 + wave * 2 + 1) << 9) + lane * 8);
    am[0] = __builtin_amdgcn_mfma_f32_16x16x32_bf16(av, bv0, am[0], 0, 0, 0);
    am[1] = __builtin_amdgcn_mfma_f32_16x16x32_bf16(av, bv1, am[1], 0, 0, 0);
  }
#pragma unroll
  for (int j = 0; j < 2; j++) {
    int col = (wave * 2 + j) * 16 + lr;
    float bb = 48.0f * b3[col];
#pragma unroll
    for (int r = 0; r < 4; r++) {
      int row = lq * 4 + r;
      xs[row * 132 + col] = nhr[row * 128 + col] + (am[j][r] + bb) * (1.0f / 30.0f);
    }
  }
  __syncthreads();

  // ---- LN1 -> usB (bf16 swz). Wave handles 4 rows; lane owns cols lane,lane+64.
  const float lg1 = ln_g[lane],      lb1v = ln_b[lane];
  const float lg2 = ln_g[lane + 64], lb2v = ln_b[lane + 64];
#pragma unroll
  for (int s = 0; s < 4; s++) {
    int row = wave * 4 + s;
    float v1 = xs[row * 132 + lane];
    float v2 = xs[row * 132 + lane + 64];
    float s1 = v1 + v2, s2 = v1 * v1 + v2 * v2;
#pragma unroll
    for (int off = 32; off >= 1; off >>= 1) {
      s1 += __shfl_xor(s1, off);
      s2 += __shfl_xor(s2, off);
    }
    float mu = s1 * (1.f / 128.f);
    float var = s2 * (1.f / 128.f) - mu * mu;
    float rstd = rsqrtf(var + 1e-5f);
    unsigned u12 = pk2((v1 - mu) * rstd * lg1 + lb1v,
                       (v2 - mu) * rstd * lg2 + lb2v);
    int sw = (row & 7);
    usB[row * 128 + (((lane >> 3) ^ sw) << 3) + (lane & 7)]       = (short)(u12 & 0xffff);
    usB[row * 128 + ((((lane >> 3) + 8) ^ sw) << 3) + (lane & 7)] = (short)(u12 >> 16);
  }
  __syncthreads();

  // ---- upd GEMM (M=16): u @ Wu ; y = nh + . + bu -> xs ----
  f32x4 au[2] = {};
#pragma unroll
  for (int kt = 0; kt < 4; kt++) {
    bf16x8 av = *reinterpret_cast<const bf16x8*>(&usB[lr * 128 + (((kt * 4 + lq) ^ (lr & 7)) << 3)]);
    bf16x8 bv0 = *reinterpret_cast<const bf16x8*>(Wup + ((kt * 8 + wave * 2 + 0) << 9) + lane * 8);
    bf16x8 bv1 = *reinterpret_cast<const bf16x8*>(Wup + ((kt * 8 + wave * 2 + 1) << 9) + lane * 8);
    au[0] = __builtin_amdgcn_mfma_f32_16x16x32_bf16(av, bv0, au[0], 0, 0, 0);
    au[1] = __builtin_amdgcn_mfma_f32_16x16x32_bf16(av, bv1, au[1], 0, 0, 0);
  }
  __syncthreads();   // xs LN1 reads done before overwrite
#pragma unroll
  for (int j = 0; j < 2; j++) {
    int col = (wave * 2 + j) * 16 + lr;
    float bb = bu[col];
#pragma unroll
    for (int r = 0; r < 4; r++) {
      int row = lq * 4 + r;
      xs[row * 132 + col] = nhr[row * 128 + col] + au[j][r] + bb;
    }
  }
  __syncthreads();

  // ---- LN2 -> out ----
#pragma unroll
  for (int s = 0; s < 4; s++) {
    int row = wave * 4 + s;
    float v1 = xs[row * 132 + lane];
    float v2 = xs[row * 132 + lane + 64];
    float s1 = v1 + v2, s2 = v1 * v1 + v2 * v2;
#pragma unroll
    for (int off = 32; off >= 1; off >>= 1) {
      s1 += __shfl_xor(s1, off);
      s2 += __shfl_xor(s2, off);
    }
    float mu = s1 * (1.f / 128.f);
    float var = s2 * (1.f / 128.f) - mu * mu;
    float rstd = rsqrtf(var + 1e-5f);
    out[(size_t)(n0 + row) * Cn + lane]      = (v1 - mu) * rstd * lg1 + lb1v;
    out[(size_t)(n0 + row) * Cn + lane + 64] = (v2 - mu) * rstd * lg2 + lb2v;
  }
}

extern "C" void kernel_launch(void* const* d_in, const int* in_sizes, int n_in,
                              void* d_out, int out_size, void* d_ws, size_t ws_size,
                              hipStream_t stream) {
  const float* node_h     = (const float*)d_in[0];
  const float* edge_h     = (const float*)d_in[1];
  const int*   edge_index = (const int*)  d_in[2];
  const float* W1 = (const float*)d_in[3];
  const float* b1 = (const float*)d_in[4];
  const float* W2 = (const float*)d_in[5];
  const float* b2 = (const float*)d_in[6];
  const float* W3 = (const float*)d_in[7];
  const float* b3 = (const float*)d_in[8];
  const float* Wu = (const float*)d_in[9];
  const float* bu = (const float*)d_in[10];
  const float* ln_g = (const float*)d_in[11];
  const float* ln_b = (const float*)d_in[12];
  float* out   = (float*)d_out;
  short* wpack = (short*)d_ws;   // 192 KiB

  pack_weights<<<48, 256, 0, stream>>>(W1, W2, W3, Wu, wpack);
  node_update_kernel<<<Bn * Nn, 256, 0, stream>>>(
      node_h, edge_h, edge_index, wpack, b1, b2, out);
  tail_kernel<<<(Bn * Nn) / G2, 256, 0, stream>>>(
      node_h, wpack, b3, bu, ln_g, ln_b, out);
}